// Round 1
// baseline (47.508 us; speedup 1.0000x reference)
//
#include <hip/hip_runtime.h>
#include <math.h>

// SphericalHarmonicsLayer, specialized for H=256, max_order=3 (derived from sizes).
//
// out[b,n] is an [H,17] tile, flat row = (b*N+n)*H + h, 17 floats per row:
//   j=0..15: real spherical harmonics l=0..3 (reference convention incl.
//            Condon-Shortley phase inside P_l^m), j=16: time channel.
//
// Roofline: 285 MB f32 writes vs ~0.2 MB reads -> HBM-write-bound (~50-70us).
// Strategy: block = one (b,n), thread = h. Stage [256][17] tile in LDS
// (stride 17 is odd -> bank-conflict-free), then coalesced float4 copy out.

namespace {
constexpr int kH = 256;
constexpr int kPerRow = 17;  // (L+1)^2 + 1 with L=3

__global__ __launch_bounds__(kH) void sh_l3_kernel(
    const float* __restrict__ x,
    const float* __restrict__ w_theta, const float* __restrict__ b_theta,
    const float* __restrict__ w_phi,   const float* __restrict__ b_phi,
    const float* __restrict__ w_time,  const float* __restrict__ b_time,
    float* __restrict__ out)
{
    __shared__ __align__(16) float lds[kH * kPerRow];  // 17408 B

    const int bn = blockIdx.x;
    const int h  = threadIdx.x;

    // Block-uniform scalar inputs.
    const float xt = x[bn * 3 + 0];
    const float xp = x[bn * 3 + 1];
    const float xm = x[bn * 3 + 2];

    const float theta = fmaf(xt, w_theta[h], b_theta[h]);
    const float phi   = fmaf(xp, w_phi[h],   b_phi[h]);
    const float tmv   = fmaf(xm, w_time[h],  b_time[h]);

    const float ct  = cosf(theta);
    const float ct2 = ct * ct;
    // Reference: s = sqrt(clip(1 - ct^2, 0))
    const float s   = sqrtf(fmaxf(1.0f - ct2, 0.0f));
    const float ss  = s * s;
    const float sss = ss * s;

    float sp, cp;
    sincosf(phi, &sp, &cp);
    const float c2  = fmaf(2.0f * cp, cp, -1.0f);  // cos 2phi
    const float sn2 = 2.0f * sp * cp;              // sin 2phi
    const float c3  = c2 * cp - sn2 * sp;          // cos 3phi
    const float sn3 = sn2 * cp + c2 * sp;          // sin 3phi

    // K(l,m)*sqrt2 constants folded with the Legendre polynomial constants.
    // Signs follow the reference's Condon-Shortley phase:
    //   P11 = -s, P21 = -3 s ct, P31 = -1.5 s (5ct^2-1), P33 = -15 s^3
    float* row = &lds[h * kPerRow];
    row[0]  = 0.28209479177387814f;
    row[1]  = -0.4886025119029199f * s * sp;                              // (1,-1)
    row[2]  = 0.4886025119029199f * ct;                                   // (1, 0)
    row[3]  = -0.4886025119029199f * s * cp;                              // (1, 1)
    row[4]  = 0.5462742152960396f * ss * sn2;                             // (2,-2)
    row[5]  = -1.0925484305920792f * (s * ct) * sp;                       // (2,-1)
    row[6]  = 0.31539156525252005f * fmaf(3.0f, ct2, -1.0f);              // (2, 0)
    row[7]  = -1.0925484305920792f * (s * ct) * cp;                       // (2, 1)
    row[8]  = 0.5462742152960396f * ss * c2;                              // (2, 2)
    row[9]  = -0.5900435899266435f * sss * sn3;                           // (3,-3)
    row[10] = 1.445305721320277f * (ss * ct) * sn2;                       // (3,-2)
    row[11] = -0.45704579946446577f * (s * fmaf(5.0f, ct2, -1.0f)) * sp;  // (3,-1)
    row[12] = 0.3731763325901154f * ct * fmaf(5.0f, ct2, -3.0f);          // (3, 0)
    row[13] = -0.45704579946446577f * (s * fmaf(5.0f, ct2, -1.0f)) * cp;  // (3, 1)
    row[14] = 1.445305721320277f * (ss * ct) * c2;                        // (3, 2)
    row[15] = -0.5900435899266435f * sss * c3;                            // (3, 3)
    row[16] = tmv;

    __syncthreads();

    // Coalesced block copy: 4352 floats = 1088 float4 = 4 full passes + 64.
    const float4* lds4 = (const float4*)lds;
    float4* out4 = (float4*)(out + (size_t)bn * (kH * kPerRow));
#pragma unroll
    for (int i = 0; i < 4; ++i)
        out4[i * kH + h] = lds4[i * kH + h];
    if (h < (kH * kPerRow / 4) - 4 * kH)  // 1088 - 1024 = 64 tail float4s
        out4[4 * kH + h] = lds4[4 * kH + h];
}
}  // namespace

extern "C" void kernel_launch(void* const* d_in, const int* in_sizes, int n_in,
                              void* d_out, int out_size, void* d_ws, size_t ws_size,
                              hipStream_t stream) {
    const float* x       = (const float*)d_in[0];
    const float* w_theta = (const float*)d_in[1];
    const float* b_theta = (const float*)d_in[2];
    const float* w_phi   = (const float*)d_in[3];
    const float* b_phi   = (const float*)d_in[4];
    const float* w_time  = (const float*)d_in[5];
    const float* b_time  = (const float*)d_in[6];
    float* out = (float*)d_out;

    const int BN = in_sizes[0] / 3;  // B*N = 16384 (one block per (b,n) pair)
    // Specialized: H == 256 (== blockDim), per-row = out_size/(BN*H) = 17 => L=3.
    sh_l3_kernel<<<dim3(BN), dim3(kH), 0, stream>>>(
        x, w_theta, b_theta, w_phi, b_phi, w_time, b_time, out);
}